// Round 6
// baseline (2678.569 us; speedup 1.0000x reference)
//
#include <hip/hip_runtime.h>
#include <hip/hip_fp16.h>

#define N_ 50000
#define E_ 800000
#define T_ 800000
#define G_ 64
#define H_ 128

__device__ __forceinline__ float siluf(float v) {
    return __fdividef(v, 1.0f + __expf(-v));
}

// bf16 helpers
__device__ __forceinline__ unsigned short f2bf(float f) {
    unsigned int u = __float_as_uint(f);
    u += 0x7fffu + ((u >> 16) & 1u);
    return (unsigned short)(u >> 16);
}
__device__ __forceinline__ unsigned int f2bf2(float a, float b) {
    return (unsigned int)f2bf(a) | ((unsigned int)f2bf(b) << 16);
}
__device__ __forceinline__ float2 bf2x2(unsigned int p) {
    return make_float2(__uint_as_float(p << 16), __uint_as_float(p & 0xffff0000u));
}

// ---------------- CSR build ----------------
__global__ __launch_bounds__(256) void k_count(const int* __restrict__ col, int* deg, int n) {
    int e = blockIdx.x * 256 + threadIdx.x;
    if (e < n) atomicAdd(&deg[col[e]], 1);
}

__global__ __launch_bounds__(256) void k_countT(const int* __restrict__ trip, int* deg, int n) {
    int t = blockIdx.x * 256 + threadIdx.x;
    if (t < n) atomicAdd(&deg[trip[3 * t + 1]], 1);
}

__global__ __launch_bounds__(1024) void k_scan(const int* __restrict__ deg, int* rowptr, int* cur, int n) {
    __shared__ int wsum[16];
    __shared__ int s_carry;
    int tid = threadIdx.x, lane = tid & 63, w = tid >> 6;
    if (tid == 0) s_carry = 0;
    __syncthreads();
    for (int base = 0; base < n; base += 1024) {
        int i = base + tid;
        int v = (i < n) ? deg[i] : 0;
        int incl = v;
        #pragma unroll
        for (int s = 1; s < 64; s <<= 1) {
            int t = __shfl_up(incl, (unsigned)s, 64);
            if (lane >= s) incl += t;
        }
        if (lane == 63) wsum[w] = incl;
        __syncthreads();
        int carry0 = s_carry;
        int wexcl = 0;
        for (int j = 0; j < w; ++j) wexcl += wsum[j];
        int excl = carry0 + wexcl + (incl - v);
        if (i < n) { rowptr[i] = excl; cur[i] = excl; }
        __syncthreads();
        if (tid == 1023) s_carry = carry0 + wexcl + incl;
        __syncthreads();
    }
    if (tid == 0) rowptr[n] = s_carry;
}

__global__ __launch_bounds__(256) void k_fill(const int* __restrict__ col, const int* __restrict__ row,
                                              int* cur, int* elist, int* slist, int n) {
    int e = blockIdx.x * 256 + threadIdx.x;
    if (e < n) {
        int pos = atomicAdd(&cur[col[e]], 1);
        elist[pos] = e;
        slist[pos] = row[e];
    }
}

__global__ __launch_bounds__(256) void k_fillT(const int* __restrict__ trip, int* cur,
                                               const float* __restrict__ dist_trip, const float* __restrict__ angle,
                                               float* __restrict__ dsort, float* __restrict__ asort, int n) {
    int t = blockIdx.x * 256 + threadIdx.x;
    if (t < n) {
        int pos = atomicAdd(&cur[trip[3 * t + 1]], 1);
        dsort[pos] = dist_trip[t];
        asort[pos] = angle[t];
    }
}

// ---------------- rbf in CSR (segment) order ----------------
__global__ __launch_bounds__(256) void k_rbfS(const int* __restrict__ elist, const float* __restrict__ dist,
                                              const float* __restrict__ freq, float* __restrict__ rbfS, int n) {
    int p = blockIdx.x * 256 + threadIdx.x;
    if (p >= n) return;
    int e = elist[p];
    float d = dist[e] * 0.2f;
    float d2 = d * d, d4 = d2 * d2, d5 = d4 * d;
    float env = __fdividef(1.0f, d) - 28.0f * d5 + 48.0f * d5 * d - 21.0f * d5 * d2;
    #pragma unroll
    for (int r = 0; r < 6; ++r) rbfS[p * 6 + r] = env * __sinf(freq[r] * d);
}

// ---------------- per-block edge factors: s8h[p][k] = silu(rbfS[p] . W1[:,k]), fp16 ----------------
__global__ __launch_bounds__(256) void k_s8h(const float* __restrict__ rbfS, const float* __restrict__ W1,
                                             __half* __restrict__ s8, int n) {
    __shared__ float W1s[48];
    int tid = threadIdx.x;
    if (tid < 48) W1s[tid] = W1[tid];
    __syncthreads();
    int p = blockIdx.x * 256 + tid;
    if (p >= n) return;
    const float2* r2 = (const float2*)&rbfS[(size_t)p * 6];
    float2 ra = r2[0], rbx = r2[1], rc = r2[2];
    float rb[6] = {ra.x, ra.y, rbx.x, rbx.y, rc.x, rc.y};
    __half out[8];
    #pragma unroll
    for (int k = 0; k < 8; ++k) {
        float u = 0.f;
        #pragma unroll
        for (int r = 0; r < 6; ++r) u += rb[r] * W1s[r * 8 + k];
        out[k] = __float2half(siluf(u));
    }
    *(uint4*)&s8[(size_t)p * 8] = *(uint4*)out;
}

// ---------------- x = atom_table[z] ----------------
__global__ __launch_bounds__(256) void k_init_x(const float* __restrict__ atab, const int* __restrict__ z,
                                                float* __restrict__ x, int n) {
    int t = blockIdx.x * 256 + threadIdx.x;
    if (t >= n * 32) return;
    int node = t >> 5, q = t & 31;
    ((float4*)x)[t] = ((const float4*)atab)[z[node] * 32 + q];
}

// ---------------- SS[n] = sum_{e in n} silu(rbf_e @ w1 + b1), persistent waves ----------------
__global__ __launch_bounds__(256) void k_embS(const int* __restrict__ rowptr, const float* __restrict__ rbfS,
                                              const float* __restrict__ w1, const float* __restrict__ b1,
                                              float* __restrict__ SS, int n) {
    int wid = blockIdx.x * 4 + (threadIdx.x >> 6);
    int wstride = gridDim.x * 4;
    int lane = threadIdx.x & 63;
    int c = lane * 2;
    float wc0[6], wc1[6];
    #pragma unroll
    for (int r = 0; r < 6; ++r) { wc0[r] = w1[r * 128 + c]; wc1[r] = w1[r * 128 + c + 1]; }
    float bb0 = b1[c], bb1 = b1[c + 1];
    for (int node = wid; node < n; node += wstride) {
        float a0 = 0.f, a1 = 0.f;
        int p0 = rowptr[node], p1 = rowptr[node + 1];
        for (int p = p0; p < p1; ++p) {
            const float2* r2 = (const float2*)&rbfS[(size_t)p * 6];
            float2 ra = r2[0], rbx = r2[1], rc = r2[2];
            float u0 = bb0 + ra.x * wc0[0] + ra.y * wc0[1] + rbx.x * wc0[2] + rbx.y * wc0[3] + rc.x * wc0[4] + rc.y * wc0[5];
            float u1 = bb1 + ra.x * wc1[0] + ra.y * wc1[1] + rbx.x * wc1[2] + rbx.y * wc1[3] + rc.x * wc1[4] + rc.y * wc1[5];
            a0 += siluf(u0);
            a1 += siluf(u1);
        }
        SS[node * 128 + c] = a0;
        SS[node * 128 + c + 1] = a1;
    }
}

// ---------------- GEMM: C = act(A @ W + bias*scale) [+ C] ; optional bf16 shadow copy ----------------
template <int BIAS_MODE, bool SILU, bool ACC, bool WBF>
__global__ __launch_bounds__(256, 2) void k_gemm(const float* __restrict__ A, const float* __restrict__ W,
                                                 const float* __restrict__ bias, const int* __restrict__ deg,
                                                 float* __restrict__ C, unsigned short* __restrict__ Ch, int M) {
    __shared__ float Wl[128 * 128];
    int tid = threadIdx.x;
    {
        const float4* W4 = (const float4*)W;
        float4* Wl4 = (float4*)Wl;
        #pragma unroll
        for (int i = 0; i < 16; ++i) Wl4[i * 256 + tid] = W4[i * 256 + tid];
    }
    int c0 = (tid & 15) * 8;
    int rg = tid >> 4;
    int row0 = blockIdx.x * 128 + rg * 8;
    float bias_c[8];
    if constexpr (BIAS_MODE != 0) {
        #pragma unroll
        for (int j = 0; j < 8; ++j) bias_c[j] = bias[c0 + j];
    }
    const float* Ar[8];
    #pragma unroll
    for (int r = 0; r < 8; ++r) {
        int rr = row0 + r;
        if (rr > M - 1) rr = M - 1;
        Ar[r] = A + (size_t)rr * 128;
    }
    __syncthreads();
    float acc[8][8];
    #pragma unroll
    for (int r = 0; r < 8; ++r)
        #pragma unroll
        for (int j = 0; j < 8; ++j) acc[r][j] = 0.f;

    for (int k0 = 0; k0 < 128; k0 += 4) {
        float4 av[8];
        #pragma unroll
        for (int r = 0; r < 8; ++r) av[r] = *(const float4*)(Ar[r] + k0);
        #pragma unroll
        for (int kk = 0; kk < 4; ++kk) {
            float4 w0 = *(float4*)&Wl[(k0 + kk) * 128 + c0];
            float4 w1 = *(float4*)&Wl[(k0 + kk) * 128 + c0 + 4];
            #pragma unroll
            for (int r = 0; r < 8; ++r) {
                float a_ = ((float*)&av[r])[kk];
                acc[r][0] += a_ * w0.x; acc[r][1] += a_ * w0.y;
                acc[r][2] += a_ * w0.z; acc[r][3] += a_ * w0.w;
                acc[r][4] += a_ * w1.x; acc[r][5] += a_ * w1.y;
                acc[r][6] += a_ * w1.z; acc[r][7] += a_ * w1.w;
            }
        }
    }
    #pragma unroll
    for (int r = 0; r < 8; ++r) {
        int row = row0 + r;
        if (row >= M) break;
        float scale = 1.f;
        if constexpr (BIAS_MODE == 2) scale = (float)deg[row];
        float vout[8];
        #pragma unroll
        for (int j = 0; j < 8; ++j) {
            float v = acc[r][j];
            if constexpr (BIAS_MODE != 0) v += bias_c[j] * scale;
            if constexpr (SILU) v = siluf(v);
            vout[j] = v;
        }
        float* Cr = &C[(size_t)row * 128 + c0];
        if constexpr (ACC) {
            float4 o0 = *(float4*)&Cr[0], o1 = *(float4*)&Cr[4];
            vout[0] += o0.x; vout[1] += o0.y; vout[2] += o0.z; vout[3] += o0.w;
            vout[4] += o1.x; vout[5] += o1.y; vout[6] += o1.z; vout[7] += o1.w;
        }
        *(float4*)&Cr[0] = make_float4(vout[0], vout[1], vout[2], vout[3]);
        *(float4*)&Cr[4] = make_float4(vout[4], vout[5], vout[6], vout[7]);
        if constexpr (WBF) {
            uint4 pk;
            pk.x = f2bf2(vout[0], vout[1]);
            pk.y = f2bf2(vout[2], vout[3]);
            pk.z = f2bf2(vout[4], vout[5]);
            pk.w = f2bf2(vout[6], vout[7]);
            *(uint4*)&Ch[(size_t)row * 128 + c0] = pk;
        }
    }
}

// ---------------- out_block gather (persistent waves, 8-deep MLP) ----------------
__global__ __launch_bounds__(256) void k_out_gather(const int* __restrict__ rowptr, const int* __restrict__ slist,
                                                    const float* __restrict__ rbfS,
                                                    const unsigned short* __restrict__ xh,
                                                    const float* __restrict__ wrbf, float* __restrict__ h, int n) {
    int wid = blockIdx.x * 4 + (threadIdx.x >> 6);
    int wstride = gridDim.x * 4;
    int lane = threadIdx.x & 63;
    int c = lane * 2;
    float wc0[6], wc1[6];
    #pragma unroll
    for (int r = 0; r < 6; ++r) { wc0[r] = wrbf[r * 128 + c]; wc1[r] = wrbf[r * 128 + c + 1]; }
    for (int node = wid; node < n; node += wstride) {
        float a0 = 0.f, a1 = 0.f;
        int p0 = rowptr[node], p1 = rowptr[node + 1];
        int p = p0;
        for (; p + 8 <= p1; p += 8) {
            int ss[8];
            #pragma unroll
            for (int u = 0; u < 8; ++u) ss[u] = slist[p + u];
            unsigned int xv[8];
            #pragma unroll
            for (int u = 0; u < 8; ++u) xv[u] = *(const unsigned int*)&xh[(size_t)ss[u] * 128 + c];
            #pragma unroll
            for (int u = 0; u < 8; ++u) {
                const float2* r2 = (const float2*)&rbfS[(size_t)(p + u) * 6];
                float2 ra = r2[0], rbx = r2[1], rc = r2[2];
                float e0 = ra.x * wc0[0] + ra.y * wc0[1] + rbx.x * wc0[2] + rbx.y * wc0[3] + rc.x * wc0[4] + rc.y * wc0[5];
                float e1 = ra.x * wc1[0] + ra.y * wc1[1] + rbx.x * wc1[2] + rbx.y * wc1[3] + rc.x * wc1[4] + rc.y * wc1[5];
                float2 xf = bf2x2(xv[u]);
                a0 += xf.x * e0;
                a1 += xf.y * e1;
            }
        }
        for (; p < p1; ++p) {
            int src = slist[p];
            const float2* r2 = (const float2*)&rbfS[(size_t)p * 6];
            float2 ra = r2[0], rbx = r2[1], rc = r2[2];
            float e0 = ra.x * wc0[0] + ra.y * wc0[1] + rbx.x * wc0[2] + rbx.y * wc0[3] + rc.x * wc0[4] + rc.y * wc0[5];
            float e1 = ra.x * wc1[0] + ra.y * wc1[1] + rbx.x * wc1[2] + rbx.y * wc1[3] + rc.x * wc1[4] + rc.y * wc1[5];
            float2 xf = bf2x2(*(const unsigned int*)&xh[(size_t)src * 128 + c]);
            a0 += xf.x * e0;
            a1 += xf.y * e1;
        }
        h[node * 128 + c] = a0;
        h[node * 128 + c + 1] = a1;
    }
}

// ---------------- P accumulate ----------------
template <bool ACC>
__global__ __launch_bounds__(256) void k_p_acc(const float* __restrict__ h, const float* __restrict__ w2col,
                                               const float* __restrict__ ob2p, float* __restrict__ P, int n) {
    int node = blockIdx.x * 4 + (threadIdx.x >> 6);
    int lane = threadIdx.x & 63;
    if (node >= n) return;
    int c = lane * 2;
    float2 hv = *(const float2*)&h[(size_t)node * 128 + c];
    float s = hv.x * w2col[c] + hv.y * w2col[c + 1];
    #pragma unroll
    for (int off = 32; off > 0; off >>= 1) s += __shfl_xor(s, off, 64);
    if (lane == 0) {
        float r = s + ob2p[0];
        if (ACC) r += P[node];
        P[node] = r;
    }
}

// ---------------- triplet SV via sorted CSR gather ----------------
__global__ __launch_bounds__(256) void k_trip_sv(const int* __restrict__ rowptrT, const float* __restrict__ dsort,
                                                 const float* __restrict__ asort, const float* __restrict__ sfreq,
                                                 const float* __restrict__ W1, float* __restrict__ SV, int n) {
    int grp = (blockIdx.x * 256 + threadIdx.x) >> 3;
    int k = threadIdx.x & 7;
    if (grp >= n) return;
    float w[24];
    #pragma unroll
    for (int i = 0; i < 24; ++i) w[i] = W1[i * 8 + k];
    float f0 = sfreq[0], f1 = sfreq[1], f2 = sfreq[2], f3 = sfreq[3], f4 = sfreq[4], f5 = sfreq[5];
    float acc = 0.f;
    int p0 = rowptrT[grp], p1 = rowptrT[grp + 1];
    for (int p = p0; p < p1; ++p) {
        float d = dsort[p] * 0.2f;
        float a = asort[p];
        float d2 = d * d, d4 = d2 * d2, d5 = d4 * d;
        float env = __fdividef(1.0f, d) - 28.0f * d5 + 48.0f * d5 * d - 21.0f * d5 * d2;
        float rb0 = env * __sinf(f0 * d), rb1 = env * __sinf(f1 * d), rb2 = env * __sinf(f2 * d);
        float rb3 = env * __sinf(f3 * d), rb4 = env * __sinf(f4 * d), rb5 = env * __sinf(f5 * d);
        float s1 = a, s2 = 1.5f * a * a - 0.5f, s3 = 2.5f * a * a * a - 1.5f * a;
        float u = rb0 * w[0] + rb1 * w[1] + rb2 * w[2] + rb3 * w[3] + rb4 * w[4] + rb5 * w[5];
        u += s1 * (rb0 * w[6] + rb1 * w[7] + rb2 * w[8] + rb3 * w[9] + rb4 * w[10] + rb5 * w[11]);
        u += s2 * (rb0 * w[12] + rb1 * w[13] + rb2 * w[14] + rb3 * w[15] + rb4 * w[16] + rb5 * w[17]);
        u += s3 * (rb0 * w[18] + rb1 * w[19] + rb2 * w[20] + rb3 * w[21] + rb4 * w[22] + rb5 * w[23]);
        acc += siluf(u);
    }
    SV[grp * 8 + k] = acc;
}

// ---------------- e2 = SV @ iw_sbf2 ----------------
__global__ __launch_bounds__(256) void k_sv_gemm(const float* __restrict__ SV, const float* __restrict__ W2,
                                                 float* __restrict__ e2, int n) {
    __shared__ float W2s[8 * 128];
    int tid = threadIdx.x;
    for (int i = tid; i < 1024; i += 256) W2s[i] = W2[i];
    __syncthreads();
    int t = blockIdx.x * 256 + tid;
    if (t >= n * 32) return;
    int node = t >> 5, q = t & 31;
    const float* sv = &SV[node * 8];
    int c = q * 4;
    float out[4] = {0.f, 0.f, 0.f, 0.f};
    #pragma unroll
    for (int k = 0; k < 8; ++k) {
        float s = sv[k];
        #pragma unroll
        for (int i = 0; i < 4; ++i) out[i] += s * W2s[k * 128 + c + i];
    }
    *(float4*)&e2[(size_t)node * 128 + c] = make_float4(out[0], out[1], out[2], out[3]);
}

// ---------------- extra[c] = sum_n t_mat[n][c] * e2[n][c] ----------------
__global__ __launch_bounds__(256) void k_extra_reduce(const float* __restrict__ Tm, const float* __restrict__ E2,
                                                      float* __restrict__ extra, int n) {
    const float4* t4 = (const float4*)Tm;
    const float4* e4 = (const float4*)E2;
    int tid = threadIdx.x;
    int q = tid & 31, rl = tid >> 5;
    float ax = 0.f, ay = 0.f, az = 0.f, aw = 0.f;
    for (int nn = blockIdx.x * 8 + rl; nn < n; nn += 1024) {
        float4 a = t4[(size_t)nn * 32 + q];
        float4 b = e4[(size_t)nn * 32 + q];
        ax += a.x * b.x; ay += a.y * b.y; az += a.z * b.z; aw += a.w * b.w;
    }
    __shared__ float4 red[256];
    red[tid] = make_float4(ax, ay, az, aw);
    __syncthreads();
    if (tid < 128) {
        float4 o = red[tid + 128];
        red[tid].x += o.x; red[tid].y += o.y; red[tid].z += o.z; red[tid].w += o.w;
    }
    __syncthreads();
    if (tid < 64) {
        float4 o = red[tid + 64];
        red[tid].x += o.x; red[tid].y += o.y; red[tid].z += o.z; red[tid].w += o.w;
    }
    __syncthreads();
    if (tid < 32) {
        float4 r = red[tid];
        float4 o = red[tid + 32];
        r.x += o.x; r.y += o.y; r.z += o.z; r.w += o.w;
        atomicAdd(&extra[tid * 4 + 0], r.x);
        atomicAdd(&extra[tid * 4 + 1], r.y);
        atomicAdd(&extra[tid * 4 + 2], r.z);
        atomicAdd(&extra[tid * 4 + 3], r.w);
    }
}

// ---------------- interaction (persistent waves, 8-deep MLP) ----------------
__global__ __launch_bounds__(256) void k_interact(const int* __restrict__ rowptr, const int* __restrict__ slist,
                                                  const __half* __restrict__ s8, const float* __restrict__ W2,
                                                  const float* __restrict__ extra,
                                                  const unsigned short* __restrict__ xuph,
                                                  float* __restrict__ x, unsigned short* __restrict__ xh, int n) {
    int wid = blockIdx.x * 4 + (threadIdx.x >> 6);
    int wstride = gridDim.x * 4;
    int lane = threadIdx.x & 63;
    int c = lane * 2;
    float w2c0[8], w2c1[8];
    #pragma unroll
    for (int k = 0; k < 8; ++k) { w2c0[k] = W2[k * 128 + c]; w2c1[k] = W2[k * 128 + c + 1]; }
    float ex0 = extra[c], ex1 = extra[c + 1];
    for (int node = wid; node < n; node += wstride) {
        int p0 = rowptr[node], p1 = rowptr[node + 1];
        float cntf = (float)(p1 - p0);
        float a0 = cntf * ex0, a1 = cntf * ex1;
        int p = p0;
        for (; p + 8 <= p1; p += 8) {
            int ss[8];
            #pragma unroll
            for (int u = 0; u < 8; ++u) ss[u] = slist[p + u];
            unsigned int xv[8];
            #pragma unroll
            for (int u = 0; u < 8; ++u) xv[u] = *(const unsigned int*)&xuph[(size_t)ss[u] * 128 + c];
            #pragma unroll
            for (int u = 0; u < 8; ++u) {
                uint4 sv = *(const uint4*)(s8 + (size_t)(p + u) * 8);
                const __half2* h2 = (const __half2*)&sv;
                float2 s01 = __half22float2(h2[0]);
                float2 s23 = __half22float2(h2[1]);
                float2 s45 = __half22float2(h2[2]);
                float2 s67 = __half22float2(h2[3]);
                float e0 = s01.x * w2c0[0] + s01.y * w2c0[1] + s23.x * w2c0[2] + s23.y * w2c0[3] +
                           s45.x * w2c0[4] + s45.y * w2c0[5] + s67.x * w2c0[6] + s67.y * w2c0[7];
                float e1 = s01.x * w2c1[0] + s01.y * w2c1[1] + s23.x * w2c1[2] + s23.y * w2c1[3] +
                           s45.x * w2c1[4] + s45.y * w2c1[5] + s67.x * w2c1[6] + s67.y * w2c1[7];
                float2 xf = bf2x2(xv[u]);
                a0 += xf.x * e0;
                a1 += xf.y * e1;
            }
        }
        for (; p < p1; ++p) {
            int src = slist[p];
            float2 xf = bf2x2(*(const unsigned int*)&xuph[(size_t)src * 128 + c]);
            uint4 sv = *(const uint4*)(s8 + (size_t)p * 8);
            const __half2* h2 = (const __half2*)&sv;
            float2 s01 = __half22float2(h2[0]);
            float2 s23 = __half22float2(h2[1]);
            float2 s45 = __half22float2(h2[2]);
            float2 s67 = __half22float2(h2[3]);
            float e0 = s01.x * w2c0[0] + s01.y * w2c0[1] + s23.x * w2c0[2] + s23.y * w2c0[3] +
                       s45.x * w2c0[4] + s45.y * w2c0[5] + s67.x * w2c0[6] + s67.y * w2c0[7];
            float e1 = s01.x * w2c1[0] + s01.y * w2c1[1] + s23.x * w2c1[2] + s23.y * w2c1[3] +
                       s45.x * w2c1[4] + s45.y * w2c1[5] + s67.x * w2c1[6] + s67.y * w2c1[7];
            a0 += xf.x * e0;
            a1 += xf.y * e1;
        }
        float nx0 = x[(size_t)node * 128 + c] + a0;
        float nx1 = x[(size_t)node * 128 + c + 1] + a1;
        x[(size_t)node * 128 + c] = nx0;
        x[(size_t)node * 128 + c + 1] = nx1;
        *(unsigned int*)&xh[(size_t)node * 128 + c] = f2bf2(nx0, nx1);
    }
}

// ---------------- pooling ----------------
__global__ __launch_bounds__(256) void k_pool(const float* __restrict__ P, const int* __restrict__ batch,
                                              float* __restrict__ pool, float* __restrict__ cnt, int n) {
    int i = blockIdx.x * 256 + threadIdx.x;
    int lane = threadIdx.x & 63;
    int b = (i < n) ? batch[i] : -1;
    float p = (i < n) ? P[i] : 0.f;
    int b0 = __shfl(b, 0, 64);
    int b63 = __shfl(b, 63, 64);
    if (b0 == b63 && b0 >= 0) {
        float s = p;
        #pragma unroll
        for (int off = 32; off > 0; off >>= 1) s += __shfl_xor(s, off, 64);
        if (lane == 0) {
            atomicAdd(&pool[b0], s);
            atomicAdd(&cnt[b0], 64.0f);
        }
    } else {
        if (i < n) {
            atomicAdd(&pool[b], p);
            atomicAdd(&cnt[b], 1.0f);
        }
    }
}

__global__ __launch_bounds__(64) void k_final(const float* __restrict__ pool, const float* __restrict__ cnt,
                                              float* __restrict__ out) {
    int g = threadIdx.x;
    if (g < G_) out[g] = __fdividef(pool[g], fmaxf(cnt[g], 1.0f));
}

extern "C" void kernel_launch(void* const* d_in, const int* in_sizes, int n_in,
                              void* d_out, int out_size, void* d_ws, size_t ws_size,
                              hipStream_t stream) {
    (void)in_sizes; (void)n_in; (void)out_size; (void)ws_size;
    const int* z = (const int*)d_in[0];
    const float* dist = (const float*)d_in[1];
    const float* dist_trip = (const float*)d_in[2];
    const float* angle = (const float*)d_in[3];
    const int* edge_index = (const int*)d_in[4];
    const int* triplets = (const int*)d_in[5];
    const int* batch = (const int*)d_in[6];
    const float* atom_table = (const float*)d_in[7];
    const float* rbf_freq = (const float*)d_in[8];
    const float* sbf_freq = (const float*)d_in[9];
    const float* emb_w1 = (const float*)d_in[10];
    const float* emb_b1 = (const float*)d_in[11];
    const float* emb_w2 = (const float*)d_in[12];
    const float* emb_b2 = (const float*)d_in[13];
    const float* iw_rbf1 = (const float*)d_in[14];
    const float* iw_rbf2 = (const float*)d_in[15];
    const float* iw_sbf1 = (const float*)d_in[16];
    const float* iw_sbf2 = (const float*)d_in[17];
    const float* iw_t1 = (const float*)d_in[18];
    const float* iw_t2 = (const float*)d_in[19];
    const float* ib_t2 = (const float*)d_in[20];
    const float* iw_up = (const float*)d_in[21];
    const float* ib_up = (const float*)d_in[22];
    const float* iw_down = (const float*)d_in[23];
    const float* ib_down = (const float*)d_in[24];
    const float* ow_rbf = (const float*)d_in[25];
    const float* ow0 = (const float*)d_in[26];
    const float* ob0 = (const float*)d_in[27];
    const float* ow1 = (const float*)d_in[28];
    const float* ob1 = (const float*)d_in[29];
    const float* ow2 = (const float*)d_in[30];
    const float* ob2 = (const float*)d_in[31];

    const int* erow = edge_index;
    const int* ecol = edge_index + E_;

    // workspace layout
    float* ws = (float*)d_ws;
    float* x = ws;                             // N*128
    float* bufA = x + (size_t)N_ * H_;         // N*128
    float* bufB = bufA + (size_t)N_ * H_;      // N*128
    float* P = bufB + (size_t)N_ * H_;         // N
    float* rbfS = P + N_;                      // E*6 (CSR order)
    float* SV = rbfS + (size_t)E_ * 6;         // N*8
    float* extra = SV + (size_t)N_ * 8;        // 128
    float* pool = extra + 128;                 // G
    float* cnt = pool + G_;                    // G
    int* deg = (int*)(cnt + G_);               // N
    int* rowptr = deg + N_;                    // N+1
    int* cur = rowptr + N_ + 1;                // N
    int* elist = cur + N_;                     // E
    int* slist = elist + E_;                   // E
    int* rowptrT = slist + E_;                 // N+1
    int* degT = rowptrT + N_ + 1;              // N
    float* dsort = (float*)(degT + N_);        // T
    float* asort = dsort + T_;                 // T
    __half* s8h = (__half*)(asort + T_);       // E*8 halves
    unsigned short* xh = (unsigned short*)(s8h + (size_t)E_ * 8);   // N*128 bf16 shadow of x
    unsigned short* xuph = xh + (size_t)N_ * H_;                    // N*128 bf16 shadow of x_up

    const int EG = (E_ + 255) / 256;
    const int TG = (T_ + 255) / 256;
    const int NG4 = (N_ + 3) / 4;
    const int GEMMG = (N_ + 127) / 128;
    const int PG = 2048;   // persistent: 8192 waves = 32/CU

    hipMemsetAsync(deg, 0, N_ * sizeof(int), stream);
    hipMemsetAsync(degT, 0, N_ * sizeof(int), stream);
    k_count<<<EG, 256, 0, stream>>>(ecol, deg, E_);
    k_countT<<<TG, 256, 0, stream>>>(triplets, degT, T_);
    k_scan<<<1, 1024, 0, stream>>>(deg, rowptr, cur, N_);
    k_fill<<<EG, 256, 0, stream>>>(ecol, erow, cur, elist, slist, E_);
    k_scan<<<1, 1024, 0, stream>>>(degT, rowptrT, cur, N_);
    k_fillT<<<TG, 256, 0, stream>>>(triplets, cur, dist_trip, angle, dsort, asort, T_);

    k_rbfS<<<EG, 256, 0, stream>>>(elist, dist, rbf_freq, rbfS, E_);
    k_init_x<<<(N_ * 32) / 256, 256, 0, stream>>>(atom_table, z, x, N_);

    k_embS<<<PG, 256, 0, stream>>>(rowptr, rbfS, emb_w1, emb_b1, bufA, N_);
    k_gemm<2, false, true, true><<<GEMMG, 256, 0, stream>>>(bufA, emb_w2, emb_b2, deg, x, xh, N_);

    auto out_block = [&](int k, bool first) {
        k_out_gather<<<PG, 256, 0, stream>>>(rowptr, slist, rbfS, xh,
                                             ow_rbf + (size_t)k * 6 * 128, bufA, N_);
        k_gemm<1, true, false, false><<<GEMMG, 256, 0, stream>>>(bufA, ow0 + (size_t)k * 16384, ob0 + k * 128,
                                                                 nullptr, bufB, nullptr, N_);
        k_gemm<1, true, false, false><<<GEMMG, 256, 0, stream>>>(bufB, ow1 + (size_t)k * 16384, ob1 + k * 128,
                                                                 nullptr, bufA, nullptr, N_);
        if (first)
            k_p_acc<false><<<NG4, 256, 0, stream>>>(bufA, ow2 + k * 128, ob2 + k, P, N_);
        else
            k_p_acc<true><<<NG4, 256, 0, stream>>>(bufA, ow2 + k * 128, ob2 + k, P, N_);
    };

    out_block(0, true);

    for (int b = 0; b < 4; ++b) {
        k_gemm<1, false, false, false><<<GEMMG, 256, 0, stream>>>(x, iw_down + (size_t)b * 16384, ib_down + b * 128,
                                                                  nullptr, bufA, nullptr, N_);
        k_gemm<0, true, false, false><<<GEMMG, 256, 0, stream>>>(bufA, iw_t1 + (size_t)b * 16384, nullptr,
                                                                 nullptr, bufB, nullptr, N_);
        k_gemm<1, false, false, false><<<GEMMG, 256, 0, stream>>>(bufB, iw_t2 + (size_t)b * 16384, ib_t2 + b * 128,
                                                                  nullptr, bufA, nullptr, N_);
        k_trip_sv<<<(N_ * 8 + 255) / 256, 256, 0, stream>>>(rowptrT, dsort, asort, sbf_freq,
                                                            iw_sbf1 + (size_t)b * 192, SV, N_);
        k_sv_gemm<<<(N_ * 32) / 256, 256, 0, stream>>>(SV, iw_sbf2 + (size_t)b * 1024, bufB, N_);
        hipMemsetAsync(extra, 0, 128 * sizeof(float), stream);
        k_extra_reduce<<<128, 256, 0, stream>>>(bufA, bufB, extra, N_);
        k_s8h<<<EG, 256, 0, stream>>>(rbfS, iw_rbf1 + (size_t)b * 48, s8h, E_);
        k_gemm<1, false, false, true><<<GEMMG, 256, 0, stream>>>(x, iw_up + (size_t)b * 16384, ib_up + b * 128,
                                                                 nullptr, bufB, xuph, N_);
        k_interact<<<PG, 256, 0, stream>>>(rowptr, slist, s8h, iw_rbf2 + (size_t)b * 1024, extra,
                                           xuph, x, xh, N_);
        out_block(b + 1, false);
    }

    hipMemsetAsync(pool, 0, 2 * G_ * sizeof(float), stream);
    k_pool<<<(N_ + 255) / 256, 256, 0, stream>>>(P, batch, pool, cnt, N_);
    k_final<<<1, 64, 0, stream>>>(pool, cnt, (float*)d_out);
}

// Round 7
// 2346.380 us; speedup vs baseline: 1.1416x; 1.1416x over previous
//
#include <hip/hip_runtime.h>
#include <hip/hip_fp16.h>

#define N_ 50000
#define E_ 800000
#define T_ 800000
#define G_ 64
#define H_ 128

typedef __attribute__((ext_vector_type(8))) short bf16x8;
typedef __attribute__((ext_vector_type(4))) float f32x4;

__device__ __forceinline__ float siluf(float v) {
    return __fdividef(v, 1.0f + __expf(-v));
}

// bf16 helpers
__device__ __forceinline__ unsigned short f2bf(float f) {
    unsigned int u = __float_as_uint(f);
    u += 0x7fffu + ((u >> 16) & 1u);
    return (unsigned short)(u >> 16);
}
__device__ __forceinline__ unsigned int f2bf2(float a, float b) {
    return (unsigned int)f2bf(a) | ((unsigned int)f2bf(b) << 16);
}
__device__ __forceinline__ float2 bf2x2(unsigned int p) {
    return make_float2(__uint_as_float(p << 16), __uint_as_float(p & 0xffff0000u));
}

// ---------------- CSR build ----------------
__global__ __launch_bounds__(256) void k_count(const int* __restrict__ col, int* deg, int n) {
    int e = blockIdx.x * 256 + threadIdx.x;
    if (e < n) atomicAdd(&deg[col[e]], 1);
}

__global__ __launch_bounds__(256) void k_countT(const int* __restrict__ trip, int* deg, int n) {
    int t = blockIdx.x * 256 + threadIdx.x;
    if (t < n) atomicAdd(&deg[trip[3 * t + 1]], 1);
}

__global__ __launch_bounds__(1024) void k_scan(const int* __restrict__ deg, int* rowptr, int* cur, int n) {
    __shared__ int wsum[16];
    __shared__ int s_carry;
    int tid = threadIdx.x, lane = tid & 63, w = tid >> 6;
    if (tid == 0) s_carry = 0;
    __syncthreads();
    for (int base = 0; base < n; base += 1024) {
        int i = base + tid;
        int v = (i < n) ? deg[i] : 0;
        int incl = v;
        #pragma unroll
        for (int s = 1; s < 64; s <<= 1) {
            int t = __shfl_up(incl, (unsigned)s, 64);
            if (lane >= s) incl += t;
        }
        if (lane == 63) wsum[w] = incl;
        __syncthreads();
        int carry0 = s_carry;
        int wexcl = 0;
        for (int j = 0; j < w; ++j) wexcl += wsum[j];
        int excl = carry0 + wexcl + (incl - v);
        if (i < n) { rowptr[i] = excl; cur[i] = excl; }
        __syncthreads();
        if (tid == 1023) s_carry = carry0 + wexcl + incl;
        __syncthreads();
    }
    if (tid == 0) rowptr[n] = s_carry;
}

__global__ __launch_bounds__(256) void k_fill(const int* __restrict__ col, const int* __restrict__ row,
                                              int* cur, int* elist, int* slist, int n) {
    int e = blockIdx.x * 256 + threadIdx.x;
    if (e < n) {
        int pos = atomicAdd(&cur[col[e]], 1);
        elist[pos] = e;
        slist[pos] = row[e];
    }
}

__global__ __launch_bounds__(256) void k_fillT(const int* __restrict__ trip, int* cur,
                                               const float* __restrict__ dist_trip, const float* __restrict__ angle,
                                               float* __restrict__ dsort, float* __restrict__ asort, int n) {
    int t = blockIdx.x * 256 + threadIdx.x;
    if (t < n) {
        int pos = atomicAdd(&cur[trip[3 * t + 1]], 1);
        dsort[pos] = dist_trip[t];
        asort[pos] = angle[t];
    }
}

// ---------------- weight prep: fp32 (k,n) -> bf16 transposed (n,k), 27 matrices ----------------
__global__ __launch_bounds__(256) void k_wprep(const float* __restrict__ emb_w2, const float* __restrict__ iw_down,
                                               const float* __restrict__ iw_t1, const float* __restrict__ iw_t2,
                                               const float* __restrict__ iw_up, const float* __restrict__ ow0,
                                               const float* __restrict__ ow1, unsigned short* __restrict__ Wt) {
    int mat = blockIdx.x >> 3;      // 0..26
    int part = blockIdx.x & 7;      // 0..7
    const float* src;
    if (mat == 0) src = emb_w2;
    else if (mat < 5) src = iw_down + (size_t)(mat - 1) * 16384;
    else if (mat < 9) src = iw_t1 + (size_t)(mat - 5) * 16384;
    else if (mat < 13) src = iw_t2 + (size_t)(mat - 9) * 16384;
    else if (mat < 17) src = iw_up + (size_t)(mat - 13) * 16384;
    else if (mat < 22) src = ow0 + (size_t)(mat - 17) * 16384;
    else src = ow1 + (size_t)(mat - 22) * 16384;
    unsigned short* dst = Wt + (size_t)mat * 16384;
    int base = part * 2048;
    for (int i = base + threadIdx.x; i < base + 2048; i += 256) {
        int k = i >> 7, n = i & 127;
        dst[n * 128 + k] = f2bf(src[i]);
    }
}

// ---------------- rbf in CSR (segment) order ----------------
__global__ __launch_bounds__(256) void k_rbfS(const int* __restrict__ elist, const float* __restrict__ dist,
                                              const float* __restrict__ freq, float* __restrict__ rbfS, int n) {
    int p = blockIdx.x * 256 + threadIdx.x;
    if (p >= n) return;
    int e = elist[p];
    float d = dist[e] * 0.2f;
    float d2 = d * d, d4 = d2 * d2, d5 = d4 * d;
    float env = __fdividef(1.0f, d) - 28.0f * d5 + 48.0f * d5 * d - 21.0f * d5 * d2;
    #pragma unroll
    for (int r = 0; r < 6; ++r) rbfS[p * 6 + r] = env * __sinf(freq[r] * d);
}

// ---------------- per-block edge factors: s8h[p][k] = silu(rbfS[p] . W1[:,k]), fp16 ----------------
__global__ __launch_bounds__(256) void k_s8h(const float* __restrict__ rbfS, const float* __restrict__ W1,
                                             __half* __restrict__ s8, int n) {
    __shared__ float W1s[48];
    int tid = threadIdx.x;
    if (tid < 48) W1s[tid] = W1[tid];
    __syncthreads();
    int p = blockIdx.x * 256 + tid;
    if (p >= n) return;
    const float2* r2 = (const float2*)&rbfS[(size_t)p * 6];
    float2 ra = r2[0], rbx = r2[1], rc = r2[2];
    float rb[6] = {ra.x, ra.y, rbx.x, rbx.y, rc.x, rc.y};
    __half out[8];
    #pragma unroll
    for (int k = 0; k < 8; ++k) {
        float u = 0.f;
        #pragma unroll
        for (int r = 0; r < 6; ++r) u += rb[r] * W1s[r * 8 + k];
        out[k] = __float2half(siluf(u));
    }
    *(uint4*)&s8[(size_t)p * 8] = *(uint4*)out;
}

// ---------------- x = atom_table[z] ----------------
__global__ __launch_bounds__(256) void k_init_x(const float* __restrict__ atab, const int* __restrict__ z,
                                                float* __restrict__ x, int n) {
    int t = blockIdx.x * 256 + threadIdx.x;
    if (t >= n * 32) return;
    int node = t >> 5, q = t & 31;
    ((float4*)x)[t] = ((const float4*)atab)[z[node] * 32 + q];
}

// ---------------- SS[n] = sum_{e in n} silu(rbf_e @ w1 + b1) ----------------
__global__ __launch_bounds__(256) void k_embS(const int* __restrict__ rowptr, const float* __restrict__ rbfS,
                                              const float* __restrict__ w1, const float* __restrict__ b1,
                                              float* __restrict__ SS, int n) {
    int node = blockIdx.x * 4 + (threadIdx.x >> 6);
    int lane = threadIdx.x & 63;
    if (node >= n) return;
    int c = lane * 2;
    float wc0[6], wc1[6];
    #pragma unroll
    for (int r = 0; r < 6; ++r) { wc0[r] = w1[r * 128 + c]; wc1[r] = w1[r * 128 + c + 1]; }
    float bb0 = b1[c], bb1 = b1[c + 1];
    float a0 = 0.f, a1 = 0.f;
    int p0 = rowptr[node], p1 = rowptr[node + 1];
    for (int p = p0; p < p1; ++p) {
        const float2* r2 = (const float2*)&rbfS[(size_t)p * 6];
        float2 ra = r2[0], rbx = r2[1], rc = r2[2];
        float u0 = bb0 + ra.x * wc0[0] + ra.y * wc0[1] + rbx.x * wc0[2] + rbx.y * wc0[3] + rc.x * wc0[4] + rc.y * wc0[5];
        float u1 = bb1 + ra.x * wc1[0] + ra.y * wc1[1] + rbx.x * wc1[2] + rbx.y * wc1[3] + rc.x * wc1[4] + rc.y * wc1[5];
        a0 += siluf(u0);
        a1 += siluf(u1);
    }
    SS[node * 128 + c] = a0;
    SS[node * 128 + c + 1] = a1;
}

// ---------------- MFMA GEMM: C = act(A @ W + bias*scale) [+ C] ----------------
// A fp32 (M,128) converted in-flight; Wt bf16 transposed (n,k). 64 rows/block, 4 waves.
// Layouts (m89-verified): A[m=lane&15][k=quad*8+j]; B[n=lane&15][k=quad*8+j]; D col=lane&15,row=quad*4+reg.
template <int BIAS_MODE, bool SILU, bool ACC, bool WBF>
__global__ __launch_bounds__(256, 4) void k_gemm_mfma(const float* __restrict__ A,
                                                      const unsigned short* __restrict__ Wt,
                                                      const float* __restrict__ bias, const int* __restrict__ deg,
                                                      float* __restrict__ C, unsigned short* __restrict__ Ch, int M) {
    int tid = threadIdx.x;
    int wave = tid >> 6, lane = tid & 63;
    int m15 = lane & 15, quad = lane >> 4;
    int row0 = blockIdx.x * 64 + wave * 16;
    int arow = row0 + m15;
    if (arow > M - 1) arow = M - 1;
    const float* Arow = A + (size_t)arow * 128;

    f32x4 acc[8];
    #pragma unroll
    for (int nt = 0; nt < 8; ++nt) acc[nt] = (f32x4){0.f, 0.f, 0.f, 0.f};

    #pragma unroll
    for (int kt = 0; kt < 4; ++kt) {
        int ks = kt * 32 + quad * 8;
        float4 a0 = *(const float4*)(Arow + ks);
        float4 a1 = *(const float4*)(Arow + ks + 4);
        union { bf16x8 v; unsigned int u[4]; } af;
        af.u[0] = f2bf2(a0.x, a0.y);
        af.u[1] = f2bf2(a0.z, a0.w);
        af.u[2] = f2bf2(a1.x, a1.y);
        af.u[3] = f2bf2(a1.z, a1.w);
        #pragma unroll
        for (int nt = 0; nt < 8; ++nt) {
            bf16x8 bf = *(const bf16x8*)(Wt + (size_t)(nt * 16 + m15) * 128 + ks);
            acc[nt] = __builtin_amdgcn_mfma_f32_16x16x32_bf16(af.v, bf, acc[nt], 0, 0, 0);
        }
    }

    #pragma unroll
    for (int nt = 0; nt < 8; ++nt) {
        int col = nt * 16 + m15;
        float bc = 0.f;
        if constexpr (BIAS_MODE != 0) bc = bias[col];
        #pragma unroll
        for (int reg = 0; reg < 4; ++reg) {
            int row = row0 + quad * 4 + reg;
            if (row < M) {
                float v = acc[nt][reg];
                if constexpr (BIAS_MODE == 1) v += bc;
                if constexpr (BIAS_MODE == 2) v += bc * (float)deg[row];
                if constexpr (SILU) v = siluf(v);
                float* cp = &C[(size_t)row * 128 + col];
                if constexpr (ACC) v += *cp;
                *cp = v;
                if constexpr (WBF) Ch[(size_t)row * 128 + col] = f2bf(v);
            }
        }
    }
}

// ---------------- out_block gather (R4-proven: 4-deep, non-persistent) ----------------
__global__ __launch_bounds__(256) void k_out_gather(const int* __restrict__ rowptr, const int* __restrict__ slist,
                                                    const float* __restrict__ rbfS,
                                                    const unsigned short* __restrict__ xh,
                                                    const float* __restrict__ wrbf, float* __restrict__ h, int n) {
    int node = blockIdx.x * 4 + (threadIdx.x >> 6);
    int lane = threadIdx.x & 63;
    if (node >= n) return;
    int c = lane * 2;
    float wc0[6], wc1[6];
    #pragma unroll
    for (int r = 0; r < 6; ++r) { wc0[r] = wrbf[r * 128 + c]; wc1[r] = wrbf[r * 128 + c + 1]; }
    float a0 = 0.f, a1 = 0.f;
    int p0 = rowptr[node], p1 = rowptr[node + 1];
    int p = p0;
    for (; p + 4 <= p1; p += 4) {
        int s0 = slist[p], s1 = slist[p + 1], s2 = slist[p + 2], s3 = slist[p + 3];
        float2 rb[4][3];
        #pragma unroll
        for (int u = 0; u < 4; ++u) {
            const float2* r2 = (const float2*)&rbfS[(size_t)(p + u) * 6];
            rb[u][0] = r2[0]; rb[u][1] = r2[1]; rb[u][2] = r2[2];
        }
        unsigned int xv0 = *(const unsigned int*)&xh[(size_t)s0 * 128 + c];
        unsigned int xv1 = *(const unsigned int*)&xh[(size_t)s1 * 128 + c];
        unsigned int xv2 = *(const unsigned int*)&xh[(size_t)s2 * 128 + c];
        unsigned int xv3 = *(const unsigned int*)&xh[(size_t)s3 * 128 + c];
        #pragma unroll
        for (int u = 0; u < 4; ++u) {
            float e0 = rb[u][0].x * wc0[0] + rb[u][0].y * wc0[1] + rb[u][1].x * wc0[2] +
                       rb[u][1].y * wc0[3] + rb[u][2].x * wc0[4] + rb[u][2].y * wc0[5];
            float e1 = rb[u][0].x * wc1[0] + rb[u][0].y * wc1[1] + rb[u][1].x * wc1[2] +
                       rb[u][1].y * wc1[3] + rb[u][2].x * wc1[4] + rb[u][2].y * wc1[5];
            float2 xf = bf2x2((u == 0) ? xv0 : (u == 1) ? xv1 : (u == 2) ? xv2 : xv3);
            a0 += xf.x * e0;
            a1 += xf.y * e1;
        }
    }
    for (; p < p1; ++p) {
        int src = slist[p];
        const float2* r2 = (const float2*)&rbfS[(size_t)p * 6];
        float2 ra = r2[0], rbx = r2[1], rc = r2[2];
        float e0 = ra.x * wc0[0] + ra.y * wc0[1] + rbx.x * wc0[2] + rbx.y * wc0[3] + rc.x * wc0[4] + rc.y * wc0[5];
        float e1 = ra.x * wc1[0] + ra.y * wc1[1] + rbx.x * wc1[2] + rbx.y * wc1[3] + rc.x * wc1[4] + rc.y * wc1[5];
        float2 xf = bf2x2(*(const unsigned int*)&xh[(size_t)src * 128 + c]);
        a0 += xf.x * e0;
        a1 += xf.y * e1;
    }
    h[node * 128 + c] = a0;
    h[node * 128 + c + 1] = a1;
}

// ---------------- P accumulate ----------------
template <bool ACC>
__global__ __launch_bounds__(256) void k_p_acc(const float* __restrict__ h, const float* __restrict__ w2col,
                                               const float* __restrict__ ob2p, float* __restrict__ P, int n) {
    int node = blockIdx.x * 4 + (threadIdx.x >> 6);
    int lane = threadIdx.x & 63;
    if (node >= n) return;
    int c = lane * 2;
    float2 hv = *(const float2*)&h[(size_t)node * 128 + c];
    float s = hv.x * w2col[c] + hv.y * w2col[c + 1];
    #pragma unroll
    for (int off = 32; off > 0; off >>= 1) s += __shfl_xor(s, off, 64);
    if (lane == 0) {
        float r = s + ob2p[0];
        if (ACC) r += P[node];
        P[node] = r;
    }
}

// ---------------- triplet SV via sorted CSR gather ----------------
__global__ __launch_bounds__(256) void k_trip_sv(const int* __restrict__ rowptrT, const float* __restrict__ dsort,
                                                 const float* __restrict__ asort, const float* __restrict__ sfreq,
                                                 const float* __restrict__ W1, float* __restrict__ SV, int n) {
    int grp = (blockIdx.x * 256 + threadIdx.x) >> 3;
    int k = threadIdx.x & 7;
    if (grp >= n) return;
    float w[24];
    #pragma unroll
    for (int i = 0; i < 24; ++i) w[i] = W1[i * 8 + k];
    float f0 = sfreq[0], f1 = sfreq[1], f2 = sfreq[2], f3 = sfreq[3], f4 = sfreq[4], f5 = sfreq[5];
    float acc = 0.f;
    int p0 = rowptrT[grp], p1 = rowptrT[grp + 1];
    for (int p = p0; p < p1; ++p) {
        float d = dsort[p] * 0.2f;
        float a = asort[p];
        float d2 = d * d, d4 = d2 * d2, d5 = d4 * d;
        float env = __fdividef(1.0f, d) - 28.0f * d5 + 48.0f * d5 * d - 21.0f * d5 * d2;
        float rb0 = env * __sinf(f0 * d), rb1 = env * __sinf(f1 * d), rb2 = env * __sinf(f2 * d);
        float rb3 = env * __sinf(f3 * d), rb4 = env * __sinf(f4 * d), rb5 = env * __sinf(f5 * d);
        float s1 = a, s2 = 1.5f * a * a - 0.5f, s3 = 2.5f * a * a * a - 1.5f * a;
        float u = rb0 * w[0] + rb1 * w[1] + rb2 * w[2] + rb3 * w[3] + rb4 * w[4] + rb5 * w[5];
        u += s1 * (rb0 * w[6] + rb1 * w[7] + rb2 * w[8] + rb3 * w[9] + rb4 * w[10] + rb5 * w[11]);
        u += s2 * (rb0 * w[12] + rb1 * w[13] + rb2 * w[14] + rb3 * w[15] + rb4 * w[16] + rb5 * w[17]);
        u += s3 * (rb0 * w[18] + rb1 * w[19] + rb2 * w[20] + rb3 * w[21] + rb4 * w[22] + rb5 * w[23]);
        acc += siluf(u);
    }
    SV[grp * 8 + k] = acc;
}

// ---------------- e2 = SV @ iw_sbf2 ----------------
__global__ __launch_bounds__(256) void k_sv_gemm(const float* __restrict__ SV, const float* __restrict__ W2,
                                                 float* __restrict__ e2, int n) {
    __shared__ float W2s[8 * 128];
    int tid = threadIdx.x;
    for (int i = tid; i < 1024; i += 256) W2s[i] = W2[i];
    __syncthreads();
    int t = blockIdx.x * 256 + tid;
    if (t >= n * 32) return;
    int node = t >> 5, q = t & 31;
    const float* sv = &SV[node * 8];
    int c = q * 4;
    float out[4] = {0.f, 0.f, 0.f, 0.f};
    #pragma unroll
    for (int k = 0; k < 8; ++k) {
        float s = sv[k];
        #pragma unroll
        for (int i = 0; i < 4; ++i) out[i] += s * W2s[k * 128 + c + i];
    }
    *(float4*)&e2[(size_t)node * 128 + c] = make_float4(out[0], out[1], out[2], out[3]);
}

// ---------------- extra[c] = sum_n t_mat[n][c] * e2[n][c] ----------------
__global__ __launch_bounds__(256) void k_extra_reduce(const float* __restrict__ Tm, const float* __restrict__ E2,
                                                      float* __restrict__ extra, int n) {
    const float4* t4 = (const float4*)Tm;
    const float4* e4 = (const float4*)E2;
    int tid = threadIdx.x;
    int q = tid & 31, rl = tid >> 5;
    float ax = 0.f, ay = 0.f, az = 0.f, aw = 0.f;
    for (int nn = blockIdx.x * 8 + rl; nn < n; nn += 1024) {
        float4 a = t4[(size_t)nn * 32 + q];
        float4 b = e4[(size_t)nn * 32 + q];
        ax += a.x * b.x; ay += a.y * b.y; az += a.z * b.z; aw += a.w * b.w;
    }
    __shared__ float4 red[256];
    red[tid] = make_float4(ax, ay, az, aw);
    __syncthreads();
    if (tid < 128) {
        float4 o = red[tid + 128];
        red[tid].x += o.x; red[tid].y += o.y; red[tid].z += o.z; red[tid].w += o.w;
    }
    __syncthreads();
    if (tid < 64) {
        float4 o = red[tid + 64];
        red[tid].x += o.x; red[tid].y += o.y; red[tid].z += o.z; red[tid].w += o.w;
    }
    __syncthreads();
    if (tid < 32) {
        float4 r = red[tid];
        float4 o = red[tid + 32];
        r.x += o.x; r.y += o.y; r.z += o.z; r.w += o.w;
        atomicAdd(&extra[tid * 4 + 0], r.x);
        atomicAdd(&extra[tid * 4 + 1], r.y);
        atomicAdd(&extra[tid * 4 + 2], r.z);
        atomicAdd(&extra[tid * 4 + 3], r.w);
    }
}

// ---------------- interaction (R4-proven: 4-deep, non-persistent) ----------------
__global__ __launch_bounds__(256) void k_interact(const int* __restrict__ rowptr, const int* __restrict__ slist,
                                                  const __half* __restrict__ s8, const float* __restrict__ W2,
                                                  const float* __restrict__ extra,
                                                  const unsigned short* __restrict__ xuph,
                                                  float* __restrict__ x, unsigned short* __restrict__ xh, int n) {
    int node = blockIdx.x * 4 + (threadIdx.x >> 6);
    int lane = threadIdx.x & 63;
    if (node >= n) return;
    int c = lane * 2;
    float w2c0[8], w2c1[8];
    #pragma unroll
    for (int k = 0; k < 8; ++k) { w2c0[k] = W2[k * 128 + c]; w2c1[k] = W2[k * 128 + c + 1]; }
    int p0 = rowptr[node], p1 = rowptr[node + 1];
    float cntf = (float)(p1 - p0);
    float a0 = cntf * extra[c], a1 = cntf * extra[c + 1];
    int p = p0;
    for (; p + 4 <= p1; p += 4) {
        int s0 = slist[p], s1 = slist[p + 1], s2 = slist[p + 2], s3 = slist[p + 3];
        uint4 sv[4];
        #pragma unroll
        for (int u = 0; u < 4; ++u) sv[u] = *(const uint4*)(s8 + (size_t)(p + u) * 8);
        unsigned int xv0 = *(const unsigned int*)&xuph[(size_t)s0 * 128 + c];
        unsigned int xv1 = *(const unsigned int*)&xuph[(size_t)s1 * 128 + c];
        unsigned int xv2 = *(const unsigned int*)&xuph[(size_t)s2 * 128 + c];
        unsigned int xv3 = *(const unsigned int*)&xuph[(size_t)s3 * 128 + c];
        #pragma unroll
        for (int u = 0; u < 4; ++u) {
            const __half2* h2 = (const __half2*)&sv[u];
            float2 s01 = __half22float2(h2[0]);
            float2 s23 = __half22float2(h2[1]);
            float2 s45 = __half22float2(h2[2]);
            float2 s67 = __half22float2(h2[3]);
            float e0 = s01.x * w2c0[0] + s01.y * w2c0[1] + s23.x * w2c0[2] + s23.y * w2c0[3] +
                       s45.x * w2c0[4] + s45.y * w2c0[5] + s67.x * w2c0[6] + s67.y * w2c0[7];
            float e1 = s01.x * w2c1[0] + s01.y * w2c1[1] + s23.x * w2c1[2] + s23.y * w2c1[3] +
                       s45.x * w2c1[4] + s45.y * w2c1[5] + s67.x * w2c1[6] + s67.y * w2c1[7];
            float2 xf = bf2x2((u == 0) ? xv0 : (u == 1) ? xv1 : (u == 2) ? xv2 : xv3);
            a0 += xf.x * e0;
            a1 += xf.y * e1;
        }
    }
    for (; p < p1; ++p) {
        int src = slist[p];
        float2 xf = bf2x2(*(const unsigned int*)&xuph[(size_t)src * 128 + c]);
        uint4 sv = *(const uint4*)(s8 + (size_t)p * 8);
        const __half2* h2 = (const __half2*)&sv;
        float2 s01 = __half22float2(h2[0]);
        float2 s23 = __half22float2(h2[1]);
        float2 s45 = __half22float2(h2[2]);
        float2 s67 = __half22float2(h2[3]);
        float e0 = s01.x * w2c0[0] + s01.y * w2c0[1] + s23.x * w2c0[2] + s23.y * w2c0[3] +
                   s45.x * w2c0[4] + s45.y * w2c0[5] + s67.x * w2c0[6] + s67.y * w2c0[7];
        float e1 = s01.x * w2c1[0] + s01.y * w2c1[1] + s23.x * w2c1[2] + s23.y * w2c1[3] +
                   s45.x * w2c1[4] + s45.y * w2c1[5] + s67.x * w2c1[6] + s67.y * w2c1[7];
        a0 += xf.x * e0;
        a1 += xf.y * e1;
    }
    float nx0 = x[(size_t)node * 128 + c] + a0;
    float nx1 = x[(size_t)node * 128 + c + 1] + a1;
    x[(size_t)node * 128 + c] = nx0;
    x[(size_t)node * 128 + c + 1] = nx1;
    *(unsigned int*)&xh[(size_t)node * 128 + c] = f2bf2(nx0, nx1);
}

// ---------------- pooling ----------------
__global__ __launch_bounds__(256) void k_pool(const float* __restrict__ P, const int* __restrict__ batch,
                                              float* __restrict__ pool, float* __restrict__ cnt, int n) {
    int i = blockIdx.x * 256 + threadIdx.x;
    int lane = threadIdx.x & 63;
    int b = (i < n) ? batch[i] : -1;
    float p = (i < n) ? P[i] : 0.f;
    int b0 = __shfl(b, 0, 64);
    int b63 = __shfl(b, 63, 64);
    if (b0 == b63 && b0 >= 0) {
        float s = p;
        #pragma unroll
        for (int off = 32; off > 0; off >>= 1) s += __shfl_xor(s, off, 64);
        if (lane == 0) {
            atomicAdd(&pool[b0], s);
            atomicAdd(&cnt[b0], 64.0f);
        }
    } else {
        if (i < n) {
            atomicAdd(&pool[b], p);
            atomicAdd(&cnt[b], 1.0f);
        }
    }
}

__global__ __launch_bounds__(64) void k_final(const float* __restrict__ pool, const float* __restrict__ cnt,
                                              float* __restrict__ out) {
    int g = threadIdx.x;
    if (g < G_) out[g] = __fdividef(pool[g], fmaxf(cnt[g], 1.0f));
}

extern "C" void kernel_launch(void* const* d_in, const int* in_sizes, int n_in,
                              void* d_out, int out_size, void* d_ws, size_t ws_size,
                              hipStream_t stream) {
    (void)in_sizes; (void)n_in; (void)out_size; (void)ws_size;
    const int* z = (const int*)d_in[0];
    const float* dist = (const float*)d_in[1];
    const float* dist_trip = (const float*)d_in[2];
    const float* angle = (const float*)d_in[3];
    const int* edge_index = (const int*)d_in[4];
    const int* triplets = (const int*)d_in[5];
    const int* batch = (const int*)d_in[6];
    const float* atom_table = (const float*)d_in[7];
    const float* rbf_freq = (const float*)d_in[8];
    const float* sbf_freq = (const float*)d_in[9];
    const float* emb_w1 = (const float*)d_in[10];
    const float* emb_b1 = (const float*)d_in[11];
    const float* emb_w2 = (const float*)d_in[12];
    const float* emb_b2 = (const float*)d_in[13];
    const float* iw_rbf1 = (const float*)d_in[14];
    const float* iw_rbf2 = (const float*)d_in[15];
    const float* iw_sbf1 = (const float*)d_in[16];
    const float* iw_sbf2 = (const float*)d_in[17];
    const float* iw_t1 = (const float*)d_in[18];
    const float* iw_t2 = (const float*)d_in[19];
    const float* ib_t2 = (const float*)d_in[20];
    const float* iw_up = (const float*)d_in[21];
    const float* ib_up = (const float*)d_in[22];
    const float* iw_down = (const float*)d_in[23];
    const float* ib_down = (const float*)d_in[24];
    const float* ow_rbf = (const float*)d_in[25];
    const float* ow0 = (const float*)d_in[26];
    const float* ob0 = (const float*)d_in[27];
    const float* ow1 = (const float*)d_in[28];
    const float* ob1 = (const float*)d_in[29];
    const float* ow2 = (const float*)d_in[30];
    const float* ob2 = (const float*)d_in[31];

    const int* erow = edge_index;
    const int* ecol = edge_index + E_;

    // workspace layout
    float* ws = (float*)d_ws;
    float* x = ws;                             // N*128
    float* bufA = x + (size_t)N_ * H_;         // N*128
    float* bufB = bufA + (size_t)N_ * H_;      // N*128
    float* P = bufB + (size_t)N_ * H_;         // N
    float* rbfS = P + N_;                      // E*6 (CSR order)
    float* SV = rbfS + (size_t)E_ * 6;         // N*8
    float* extra = SV + (size_t)N_ * 8;        // 128
    float* pool = extra + 128;                 // G
    float* cnt = pool + G_;                    // G
    int* deg = (int*)(cnt + G_);               // N
    int* rowptr = deg + N_;                    // N+1
    int* cur = rowptr + N_ + 1;                // N
    int* elist = cur + N_;                     // E
    int* slist = elist + E_;                   // E
    int* rowptrT = slist + E_;                 // N+1
    int* degT = rowptrT + N_ + 1;              // N
    float* dsort = (float*)(degT + N_);        // T
    float* asort = dsort + T_;                 // T
    __half* s8h = (__half*)(asort + T_);       // E*8 halves
    unsigned short* xh = (unsigned short*)(s8h + (size_t)E_ * 8);   // N*128 bf16 shadow of x
    unsigned short* xuph = xh + (size_t)N_ * H_;                    // N*128 bf16 shadow of x_up
    unsigned short* Wt = xuph + (size_t)N_ * H_;                    // 27*16384 bf16 transposed weights

    const int EG = (E_ + 255) / 256;
    const int TG = (T_ + 255) / 256;
    const int NG4 = (N_ + 3) / 4;
    const int GEMMG = (N_ + 63) / 64;   // 782 blocks, 64 rows each

    hipMemsetAsync(deg, 0, N_ * sizeof(int), stream);
    hipMemsetAsync(degT, 0, N_ * sizeof(int), stream);
    k_wprep<<<27 * 8, 256, 0, stream>>>(emb_w2, iw_down, iw_t1, iw_t2, iw_up, ow0, ow1, Wt);
    k_count<<<EG, 256, 0, stream>>>(ecol, deg, E_);
    k_countT<<<TG, 256, 0, stream>>>(triplets, degT, T_);
    k_scan<<<1, 1024, 0, stream>>>(deg, rowptr, cur, N_);
    k_fill<<<EG, 256, 0, stream>>>(ecol, erow, cur, elist, slist, E_);
    k_scan<<<1, 1024, 0, stream>>>(degT, rowptrT, cur, N_);
    k_fillT<<<TG, 256, 0, stream>>>(triplets, cur, dist_trip, angle, dsort, asort, T_);

    k_rbfS<<<EG, 256, 0, stream>>>(elist, dist, rbf_freq, rbfS, E_);
    k_init_x<<<(N_ * 32) / 256, 256, 0, stream>>>(atom_table, z, x, N_);

    // embedding: x += segsum(silu(rbf@w1+b1)) @ w2 + deg*b2 ; writes bf16 shadow xh
    k_embS<<<NG4, 256, 0, stream>>>(rowptr, rbfS, emb_w1, emb_b1, bufA, N_);
    k_gemm_mfma<2, false, true, true><<<GEMMG, 256, 0, stream>>>(bufA, Wt, emb_b2, deg, x, xh, N_);

    auto out_block = [&](int k, bool first) {
        k_out_gather<<<NG4, 256, 0, stream>>>(rowptr, slist, rbfS, xh,
                                              ow_rbf + (size_t)k * 6 * 128, bufA, N_);
        k_gemm_mfma<1, true, false, false><<<GEMMG, 256, 0, stream>>>(bufA, Wt + (size_t)(17 + k) * 16384,
                                                                      ob0 + k * 128, nullptr, bufB, nullptr, N_);
        k_gemm_mfma<1, true, false, false><<<GEMMG, 256, 0, stream>>>(bufB, Wt + (size_t)(22 + k) * 16384,
                                                                      ob1 + k * 128, nullptr, bufA, nullptr, N_);
        if (first)
            k_p_acc<false><<<NG4, 256, 0, stream>>>(bufA, ow2 + k * 128, ob2 + k, P, N_);
        else
            k_p_acc<true><<<NG4, 256, 0, stream>>>(bufA, ow2 + k * 128, ob2 + k, P, N_);
    };

    out_block(0, true);

    for (int b = 0; b < 4; ++b) {
        k_gemm_mfma<1, false, false, false><<<GEMMG, 256, 0, stream>>>(x, Wt + (size_t)(1 + b) * 16384,
                                                                       ib_down + b * 128, nullptr, bufA, nullptr, N_);
        k_gemm_mfma<0, true, false, false><<<GEMMG, 256, 0, stream>>>(bufA, Wt + (size_t)(5 + b) * 16384,
                                                                      nullptr, nullptr, bufB, nullptr, N_);
        k_gemm_mfma<1, false, false, false><<<GEMMG, 256, 0, stream>>>(bufB, Wt + (size_t)(9 + b) * 16384,
                                                                       ib_t2 + b * 128, nullptr, bufA, nullptr, N_);
        k_trip_sv<<<(N_ * 8 + 255) / 256, 256, 0, stream>>>(rowptrT, dsort, asort, sbf_freq,
                                                            iw_sbf1 + (size_t)b * 192, SV, N_);
        k_sv_gemm<<<(N_ * 32) / 256, 256, 0, stream>>>(SV, iw_sbf2 + (size_t)b * 1024, bufB, N_);
        hipMemsetAsync(extra, 0, 128 * sizeof(float), stream);
        k_extra_reduce<<<128, 256, 0, stream>>>(bufA, bufB, extra, N_);
        k_s8h<<<EG, 256, 0, stream>>>(rbfS, iw_rbf1 + (size_t)b * 48, s8h, E_);
        k_gemm_mfma<1, false, false, true><<<GEMMG, 256, 0, stream>>>(x, Wt + (size_t)(13 + b) * 16384,
                                                                      ib_up + b * 128, nullptr, bufB, xuph, N_);
        k_interact<<<NG4, 256, 0, stream>>>(rowptr, slist, s8h, iw_rbf2 + (size_t)b * 1024, extra,
                                            xuph, x, xh, N_);
        out_block(b + 1, false);
    }

    hipMemsetAsync(pool, 0, 2 * G_ * sizeof(float), stream);
    k_pool<<<(N_ + 255) / 256, 256, 0, stream>>>(P, batch, pool, cnt, N_);
    k_final<<<1, 64, 0, stream>>>(pool, cnt, (float*)d_out);
}